// Round 8
// baseline (493.478 us; speedup 1.0000x reference)
//
#include <hip/hip_runtime.h>
#include <hip/hip_cooperative_groups.h>
#include <stdint.h>

namespace cg = cooperative_groups;

#define B_  16
#define C_  256
#define HW_ 4096
#define Hp  66
#define PP  4356   // 66*66
#define EPS_ 1e-5f

typedef unsigned short u16;
typedef unsigned int   u32;
typedef __attribute__((ext_vector_type(4))) float  f32x4;
typedef __attribute__((ext_vector_type(8))) __bf16 bf16x8;
typedef __attribute__((ext_vector_type(8))) u16    u16x8;

__device__ __forceinline__ float bf2f(u16 u){ u32 x = ((u32)u)<<16; float f; __builtin_memcpy(&f,&x,4); return f; }
__device__ __forceinline__ u16 f2bf(float f){ u32 x; __builtin_memcpy(&x,&f,4); u32 r = x + 0x7fffu + ((x>>16)&1u); return (u16)(r>>16); }

__device__ __forceinline__ void g2l16(const void* g, void* l){
  __builtin_amdgcn_global_load_lds((__attribute__((address_space(1))) void*)(void*)g,
                                   (__attribute__((address_space(3))) void*)l, 16, 0, 0);
}
__device__ __forceinline__ bf16x8 ldfrag(const u16* p){
  u16x8 r = *(const u16x8*)p;
  return __builtin_bit_cast(bf16x8, r);
}

// ---------------- K0: pad+transpose x AND repack weights (merged, block-range split) -----
__global__ __launch_bounds__(256) void k_prep(const float* __restrict__ x, u16* __restrict__ xpT,
    const float* __restrict__ conv_w, const float* __restrict__ wq, const float* __restrict__ wo,
    const float* __restrict__ wk, const float* __restrict__ wv, const float* __restrict__ ctx,
    u16* __restrict__ wBt, u16* __restrict__ wqB, u16* __restrict__ woB,
    u16* __restrict__ wkvB, u16* __restrict__ ctxB, float* __restrict__ stats){
  __shared__ float Lt[64*65];
  int bid = blockIdx.x; int tid = threadIdx.x;
  if(bid >= 1056){
    int i = (bid-1056)*256 + tid;
    if(i < 589824){
      int j = i&7, co = (i>>3)&255, atom = (i>>11)&3, g = i>>13;   // g in [0,72)
      int t = g%9, cic = g/9;
      int ciF = cic*32 + atom*8 + j;
      wBt[i] = f2bf(conv_w[(co*256+ciF)*9 + t]); return;
    }
    i -= 589824;
    if(i < 65536){ wqB[i] = f2bf(wq[i]); return; } i -= 65536;
    if(i < 65536){ woB[i] = f2bf(wo[i]); return; } i -= 65536;
    if(i < 196608){ wkvB[i] = f2bf(wk[i]); return; } i -= 196608;
    if(i < 196608){ wkvB[196608+i] = f2bf(wv[i]); return; } i -= 196608;
    if(i < 946176){ ctxB[i] = f2bf(ctx[i]); return; } i -= 946176;
    if(i < 512){ stats[i] = 0.f; }
    return;
  }
  int b = bid/66, hh = bid - b*66;
  if(hh==0 || hh==65){
    for(int i=tid;i<32*264;i+=256){
      int pl = i/264, off = i - pl*264;
      u32* p = (u32*)(xpT + ((size_t)(b*32+pl)*PP + (size_t)hh*Hp)*8);
      p[off] = 0u;
    }
    return;
  }
  {
    int pl = tid>>3, q = tid&7;
    size_t base = ((size_t)(b*32+pl)*PP + (size_t)hh*Hp + (q>=4?65:0))*8;
    ((u32*)(xpT + base))[q&3] = 0u;
  }
  int h = hh-1;
  for(int cc=0; cc<4; cc++){
    int c0=cc*64;
    int ci = tid>>2, w0 = (tid&3)*16;
    const float* xs = x + ((size_t)(b*C_ + c0+ci)*HW_) + h*64 + w0;
    for(int j=0;j<4;j++){
      float4 v = *(const float4*)(xs + j*4);
      Lt[ci*65 + w0 + j*4 + 0] = v.x;
      Lt[ci*65 + w0 + j*4 + 1] = v.y;
      Lt[ci*65 + w0 + j*4 + 2] = v.z;
      Lt[ci*65 + w0 + j*4 + 3] = v.w;
    }
    __syncthreads();
    int w = tid>>2, cj = (tid&3)*16;
    union { u16 u[16]; uint4 v[2]; } outu;
    for(int j=0;j<16;j++) outu.u[j] = f2bf(Lt[(cj+j)*65 + w]);
    int chan = c0 + cj;
    int cic = chan>>5, at0 = (chan>>3)&3;
    u16* dst = xpT + (((size_t)(b*8+cic)*4 + at0)*PP + (size_t)hh*Hp + w + 1)*8;
    *(uint4*)dst = outu.v[0];
    *(uint4*)(dst + (size_t)PP*8) = outu.v[1];
    __syncthreads();
  }
}

// ---------------- K2: COOPERATIVE fused conv + GN stats + grid.sync + GN/SiLU/qproj -----
// Fix vs last round: stats reads after grid.sync use agent-scope ATOMIC loads +
// reader-side __threadfence() — plain loads can be served by non-coherent per-XCD
// L2 inside a single kernel (kernel-boundary flush no longer exists here).
__global__ __launch_bounds__(256, 2) void k_cgq(const u16* __restrict__ xpT, const u16* __restrict__ wBt,
    const float* __restrict__ conv_b, float* stats,
    const u16* __restrict__ wqB, const float* __restrict__ gnw, const float* __restrict__ gnb,
    const float* __restrict__ bq, u16* __restrict__ qb){
  __shared__ u16 SM[33280];       // 66,560 B pool
  u16* As = SM;                   // conv: 2 x 264x32 = 16,896 u16
  u16* Bs = SM + 16896;           // conv: 2 x 256x32 = 16,384 u16
  u16* Hl = SM;                   // qgn phase: [oct(32)][px(128)][8] = 32,768 u16 (overlay)
  int bid = blockIdx.x;
  int b = bid >> 5, hp = bid & 31;
  int tid = threadIdx.x;
  int w = tid>>6, lane = tid&63, ln = lane&15, qd = lane>>4;
  int wm = w&1, wn = w>>1;
  f32x4 acc[4][8] = {};
  int hr_[4], wp_[4];
  #pragma unroll
  for(int mf=0;mf<4;mf++){ int p = wm*64 + mf*16 + ln; hr_[mf] = p>>6; wp_[mf] = p&63; }

  #pragma unroll
  for(int r=0;r<5;r++){
    int c = r*256 + tid;
    if(c < 1056){
      int atom = c/264, ipix = c - atom*264;
      g2l16(xpT + (((size_t)(b*8+0)*4 + atom)*PP + hp*132 + ipix)*8, &As[c*8]);
    }
  }
  #pragma unroll
  for(int r=0;r<4;r++){
    int c = r*256 + tid;
    g2l16(wBt + (size_t)c*8, &Bs[c*8]);
  }
  __syncthreads();

  int cb = 0;
  for(int ci=0; ci<8; ci++){
    int ca = ci&1;
    for(int t=0;t<9;t++){
      int tn = t+1, cin = ci;
      if(tn==9){ tn=0; cin=ci+1; }
      if(cin < 8){
        #pragma unroll
        for(int r=0;r<4;r++){
          int c = r*256 + tid;
          g2l16(wBt + ((size_t)(cin*9+tn)*8192 + c*8), &Bs[(cb^1)*8192 + c*8]);
        }
      }
      if(t<5 && ci<7){
        int c = t*256 + tid;
        if(c < 1056){
          int atom = c/264, ipix = c - atom*264;
          g2l16(xpT + (((size_t)(b*8+ci+1)*4 + atom)*PP + hp*132 + ipix)*8, &As[(ca^1)*8448 + c*8]);
        }
      }
      int dy = (t*11)>>5, dx = t - dy*3;
      bf16x8 af[4], bfv[8];
      #pragma unroll
      for(int mf=0;mf<4;mf++){
        int ipix = (hr_[mf]+dy)*66 + wp_[mf] + dx;
        af[mf] = ldfrag(&As[ca*8448 + (qd*264 + ipix)*8]);
      }
      #pragma unroll
      for(int nf=0;nf<8;nf++) bfv[nf] = ldfrag(&Bs[cb*8192 + (qd*256 + wn*128+nf*16+ln)*8]);
      #pragma unroll
      for(int mf=0;mf<4;mf++)
        #pragma unroll
        for(int nf=0;nf<8;nf++)
          acc[mf][nf] = __builtin_amdgcn_mfma_f32_16x16x32_bf16(af[mf], bfv[nf], acc[mf][nf], 0,0,0);
      __syncthreads();
      cb ^= 1;
    }
  }

  // epilogue: h -> LDS tile + stats
  float s[4]={0,0,0,0}, q[4]={0,0,0,0};
  #pragma unroll
  for(int nf=0;nf<8;nf++){
    int n = wn*128 + nf*16 + ln;
    float bias = conv_b[n];
    int oct = n>>3, sub = n&7;
    #pragma unroll
    for(int mf=0;mf<4;mf++){
      #pragma unroll
      for(int r=0;r<4;r++){
        int p = wm*64 + mf*16 + qd*4 + r;
        float v = acc[mf][nf][r] + bias;
        Hl[(oct*128 + p)*8 + sub] = f2bf(v);
        s[nf>>1]+=v; q[nf>>1]+=v*v;
      }
    }
  }
  for(int off=32;off>=1;off>>=1){
    #pragma unroll
    for(int g=0;g<4;g++){ s[g]+=__shfl_down(s[g],off,64); q[g]+=__shfl_down(q[g],off,64); }
  }
  if(lane==0){
    #pragma unroll
    for(int g=0;g<4;g++){
      atomicAdd(&stats[(b*8 + wn*4 + g)*2+0], s[g]);
      atomicAdd(&stats[(b*8 + wn*4 + g)*2+1], q[g]);
    }
  }
  __threadfence();
  cg::this_grid().sync();
  __threadfence();                 // acquire: invalidate stale cache lines before stats reads

  // ---- qproj: q = silu(gn(h)) @ wq^T + bq ----
  float mean_[8], rstd_[8];
  #pragma unroll
  for(int g=0;g<8;g++){
    float sm = __hip_atomic_load(&stats[(b*8+g)*2+0], __ATOMIC_RELAXED, __HIP_MEMORY_SCOPE_AGENT);
    float qm = __hip_atomic_load(&stats[(b*8+g)*2+1], __ATOMIC_RELAXED, __HIP_MEMORY_SCOPE_AGENT);
    float mn = sm*(1.f/131072.f);
    mean_[g] = mn;
    rstd_[g] = rsqrtf(qm*(1.f/131072.f) - mn*mn + EPS_);
  }
  f32x4 a2[4][8] = {};
  #pragma unroll
  for(int kt=0;kt<8;kt++){
    float mn = mean_[kt], rsd = rstd_[kt];
    int co0 = kt*32 + qd*8;
    float4 gw0 = *(const float4*)(gnw+co0), gw1 = *(const float4*)(gnw+co0+4);
    float4 gb0 = *(const float4*)(gnb+co0), gb1 = *(const float4*)(gnb+co0+4);
    float gw[8] = {gw0.x,gw0.y,gw0.z,gw0.w, gw1.x,gw1.y,gw1.z,gw1.w};
    float gb[8] = {gb0.x,gb0.y,gb0.z,gb0.w, gb1.x,gb1.y,gb1.z,gb1.w};
    bf16x8 af[4], bfv[8];
    #pragma unroll
    for(int mf=0;mf<4;mf++){
      int row = wm*64 + mf*16 + ln;
      u16x8 hv = *(const u16x8*)&Hl[((kt*4+qd)*128 + row)*8];
      union { u16 u[8]; u16x8 v; } o;
      #pragma unroll
      for(int j=0;j<8;j++){
        float v = bf2f(hv[j]);
        v = (v-mn)*rsd*gw[j] + gb[j];
        o.u[j] = f2bf(v/(1.f+__expf(-v)));
      }
      af[mf] = __builtin_bit_cast(bf16x8, o.v);
    }
    #pragma unroll
    for(int nf=0;nf<8;nf++)
      bfv[nf] = ldfrag(wqB + (size_t)(wn*128+nf*16+ln)*256 + kt*32 + qd*8);
    #pragma unroll
    for(int mf=0;mf<4;mf++)
      #pragma unroll
      for(int nf=0;nf<8;nf++)
        a2[mf][nf] = __builtin_amdgcn_mfma_f32_16x16x32_bf16(af[mf], bfv[nf], a2[mf][nf], 0,0,0);
  }
  #pragma unroll
  for(int nf=0;nf<8;nf++){
    int n = wn*128 + nf*16 + ln;
    float bias = bq[n];
    #pragma unroll
    for(int mf=0;mf<4;mf++){
      #pragma unroll
      for(int r=0;r<4;r++){
        int ml = wm*64 + mf*16 + qd*4 + r;
        qb[((size_t)(bid*128+ml))*256 + n] = f2bf(a2[mf][nf][r]+bias);
      }
    }
  }
}

// ---------------- Fallback pair (R6, proven 338.8us) if cooperative launch fails -------
__global__ __launch_bounds__(256, 3) void k_conv_fb(const u16* __restrict__ xpT, const u16* __restrict__ wBt,
    const float* __restrict__ conv_b, u16* __restrict__ h, float* __restrict__ stats){
  __shared__ u16 As[2][264*32];
  __shared__ u16 Bs[2][128*32];
  int bid0 = blockIdx.x;
  int l = (bid0 & 7)*128 + (bid0 >> 3);
  int b = l >> 6, hp = (l >> 1) & 31, nh = l & 1;
  int tid = threadIdx.x;
  int w = tid>>6, lane = tid&63, ln = lane&15, qd = lane>>4;
  int wm = w&1, wn = w>>1;
  f32x4 acc[4][4] = {};
  int hr_[4], wp_[4];
  #pragma unroll
  for(int mf=0;mf<4;mf++){ int p = wm*64 + mf*16 + ln; hr_[mf] = p>>6; wp_[mf] = p&63; }
  #pragma unroll
  for(int r=0;r<5;r++){
    int c = r*256 + tid;
    if(c < 1056){
      int atom = c/264, ipix = c - atom*264;
      g2l16(xpT + (((size_t)(b*8+0)*4 + atom)*PP + hp*132 + ipix)*8, &As[0][c*8]);
    }
  }
  #pragma unroll
  for(int r=0;r<2;r++){
    int c = r*256 + tid;
    int atom = c>>7, col = c&127;
    g2l16(wBt + ((size_t)atom*2048 + (nh*128+col)*8), &Bs[0][c*8]);
  }
  __syncthreads();
  int cb = 0;
  for(int ci=0; ci<8; ci++){
    int ca = ci&1;
    for(int t=0;t<9;t++){
      int tn = t+1, cin = ci;
      if(tn==9){ tn=0; cin=ci+1; }
      if(cin < 8){
        #pragma unroll
        for(int r=0;r<2;r++){
          int c = r*256 + tid;
          int atom = c>>7, col = c&127;
          g2l16(wBt + (((size_t)(cin*9+tn)*4 + atom)*2048 + (nh*128+col)*8), &Bs[cb^1][c*8]);
        }
      }
      if(t<5 && ci<7){
        int c = t*256 + tid;
        if(c < 1056){
          int atom = c/264, ipix = c - atom*264;
          g2l16(xpT + (((size_t)(b*8+ci+1)*4 + atom)*PP + hp*132 + ipix)*8, &As[ca^1][c*8]);
        }
      }
      int dy = (t*11)>>5, dx = t - dy*3;
      bf16x8 af[4], bfv[4];
      #pragma unroll
      for(int mf=0;mf<4;mf++){
        int ipix = (hr_[mf]+dy)*66 + wp_[mf] + dx;
        af[mf] = ldfrag(&As[ca][(qd*264 + ipix)*8]);
      }
      #pragma unroll
      for(int nf=0;nf<4;nf++) bfv[nf] = ldfrag(&Bs[cb][(qd*128 + wn*64+nf*16+ln)*8]);
      #pragma unroll
      for(int mf=0;mf<4;mf++)
        #pragma unroll
        for(int nf=0;nf<4;nf++)
          acc[mf][nf] = __builtin_amdgcn_mfma_f32_16x16x32_bf16(af[mf], bfv[nf], acc[mf][nf], 0,0,0);
      __syncthreads();
      cb ^= 1;
    }
  }
  float s[2]={0,0}, q[2]={0,0};
  int p0 = hp*128;
  for(int nf=0;nf<4;nf++){
    int n = nh*128 + wn*64 + nf*16 + ln;
    float bias = conv_b[n];
    for(int mf=0;mf<4;mf++){
      for(int r=0;r<4;r++){
        int p = wm*64 + mf*16 + qd*4 + r;
        float v = acc[mf][nf][r] + bias;
        h[((size_t)(b*HW_ + p0 + p))*C_ + n] = f2bf(v);
        s[nf>>1]+=v; q[nf>>1]+=v*v;
      }
    }
  }
  for(int off=32;off>=1;off>>=1){
    #pragma unroll
    for(int g=0;g<2;g++){ s[g]+=__shfl_down(s[g],off,64); q[g]+=__shfl_down(q[g],off,64); }
  }
  if(lane==0){
    #pragma unroll
    for(int g=0;g<2;g++){
      int gg = nh*4 + wn*2 + g;
      atomicAdd(&stats[(b*8 + gg)*2+0], s[g]);
      atomicAdd(&stats[(b*8 + gg)*2+1], q[g]);
    }
  }
}

__global__ __launch_bounds__(256, 2) void k_qgn_fb(const u16* __restrict__ hbuf, const u16* __restrict__ wqB,
    const float* __restrict__ stats, const float* __restrict__ gnw, const float* __restrict__ gnb,
    const float* __restrict__ bq, u16* __restrict__ qb){
  __shared__ u16 As[128*32];
  __shared__ u16 Bs[256*32];
  int mt = blockIdx.x;
  int b = mt >> 5;
  int tid = threadIdx.x;
  int w = tid>>6, lane = tid&63, ln = lane&15, qd = lane>>4;
  int wm = w&1, wn = w>>1;
  int pr = tid>>1, half = tid&1;
  const u16* hsrc = hbuf + ((size_t)(mt*128+pr))*256 + half*16;
  f32x4 acc[4][8] = {};
  uint4 ra0, ra1, rb0, rb1;
  ra0 = *(const uint4*)(hsrc);
  ra1 = *(const uint4*)(hsrc + 8);
  for(int kt=0; kt<8; kt++){
    float sm = stats[(b*8+kt)*2], qm = stats[(b*8+kt)*2+1];
    float mean = sm*(1.f/131072.f);
    float rstd = rsqrtf(qm*(1.f/131072.f) - mean*mean + EPS_);
    int c0 = kt*32 + half*16;
    float4 gw0 = *(const float4*)(gnw+c0), gw1 = *(const float4*)(gnw+c0+4);
    float4 gw2 = *(const float4*)(gnw+c0+8), gw3 = *(const float4*)(gnw+c0+12);
    float4 gb0 = *(const float4*)(gnb+c0), gb1 = *(const float4*)(gnb+c0+4);
    float4 gb2 = *(const float4*)(gnb+c0+8), gb3 = *(const float4*)(gnb+c0+12);
    float gwv[16] = {gw0.x,gw0.y,gw0.z,gw0.w, gw1.x,gw1.y,gw1.z,gw1.w,
                     gw2.x,gw2.y,gw2.z,gw2.w, gw3.x,gw3.y,gw3.z,gw3.w};
    float gbv[16] = {gb0.x,gb0.y,gb0.z,gb0.w, gb1.x,gb1.y,gb1.z,gb1.w,
                     gb2.x,gb2.y,gb2.z,gb2.w, gb3.x,gb3.y,gb3.z,gb3.w};
    u16 inu[16];
    ((uint4*)inu)[0] = ra0; ((uint4*)inu)[1] = ra1;
    u16 outu[16];
    #pragma unroll
    for(int j=0;j<16;j++){
      float v = bf2f(inu[j]);
      v = (v-mean)*rstd*gwv[j] + gbv[j];
      float s = v/(1.f+__expf(-v));
      outu[j] = f2bf(s);
    }
    u16* adst = &As[pr*32 + half*16];
    ((uint4*)adst)[0] = ((uint4*)outu)[0];
    ((uint4*)adst)[1] = ((uint4*)outu)[1];
    #pragma unroll
    for(int r=0;r<4;r++){
      int c = r*256 + tid;
      int co = c>>2, atom = c&3;
      g2l16(wqB + (size_t)co*256 + kt*32 + atom*8, &Bs[c*8]);
    }
    if(kt<7){
      rb0 = *(const uint4*)(hsrc + (kt+1)*32);
      rb1 = *(const uint4*)(hsrc + (kt+1)*32 + 8);
    }
    __syncthreads();
    bf16x8 af[4], bfv[8];
    #pragma unroll
    for(int mf=0;mf<4;mf++) af[mf] = ldfrag(&As[(wm*64+mf*16+ln)*32 + qd*8]);
    #pragma unroll
    for(int nf=0;nf<8;nf++) bfv[nf] = ldfrag(&Bs[(wn*128+nf*16+ln)*32 + qd*8]);
    #pragma unroll
    for(int mf=0;mf<4;mf++)
      #pragma unroll
      for(int nf=0;nf<8;nf++)
        acc[mf][nf] = __builtin_amdgcn_mfma_f32_16x16x32_bf16(af[mf], bfv[nf], acc[mf][nf], 0,0,0);
    __syncthreads();
    ra0 = rb0; ra1 = rb1;
  }
  for(int nf=0;nf<8;nf++){
    int n = wn*128 + nf*16 + ln;
    float bias = bq[n];
    for(int mf=0;mf<4;mf++){
      for(int r=0;r<4;r++){
        int ml = wm*64 + mf*16 + qd*4 + r;
        qb[((size_t)(mt*128+ml))*256 + n] = f2bf(acc[mf][nf][r]+bias);
      }
    }
  }
}

// ---------------- K6: k,v = ctx @ {wk,wv}^T + b, 64x64 tiles, 160 blocks ----------------
__global__ __launch_bounds__(256) void k_kvproj(const u16* __restrict__ ctxB, const u16* __restrict__ wkvB,
    const float* __restrict__ bk, const float* __restrict__ bv,
    u16* __restrict__ kb, u16* __restrict__ vT){
  __shared__ u16 As[64*128];
  __shared__ u16 Bs[64*128];
  int bid = blockIdx.x;
  int nt = bid & 7, mt = bid >> 3;
  int n0 = nt*64, m0 = mt*64;
  int tid=threadIdx.x, w=tid>>6, lane=tid&63, ln=lane&15, qd=lane>>4;
  int wm = w&1, wn = w>>1;
  f32x4 acc[2][2]={};
  for(int kt=0;kt<6;kt++){
    #pragma unroll
    for(int r=0;r<4;r++){
      int c = r*256 + tid;
      int row = c>>4, atom = c&15;
      g2l16(ctxB + ((size_t)(m0+row)*768 + kt*128 + atom*8), &As[c*8]);
      g2l16(wkvB + ((size_t)(n0+row)*768 + kt*128 + atom*8), &Bs[c*8]);
    }
    __syncthreads();
    #pragma unroll
    for(int kk=0;kk<4;kk++){
      bf16x8 af[2], bfv[2];
      #pragma unroll
      for(int mf=0;mf<2;mf++) af[mf]=ldfrag(&As[(wm*32+mf*16+ln)*128 + kk*32 + qd*8]);
      #pragma unroll
      for(int nf=0;nf<2;nf++) bfv[nf]=ldfrag(&Bs[(wn*32+nf*16+ln)*128 + kk*32 + qd*8]);
      #pragma unroll
      for(int mf=0;mf<2;mf++)
        #pragma unroll
        for(int nf=0;nf<2;nf++)
          acc[mf][nf]=__builtin_amdgcn_mfma_f32_16x16x32_bf16(af[mf],bfv[nf],acc[mf][nf],0,0,0);
    }
    __syncthreads();
  }
  for(int mf=0;mf<2;mf++) for(int nf=0;nf<2;nf++){
    int ng = n0 + wn*32 + nf*16 + ln;
    float bias = ng<256 ? bk[ng] : bv[ng-256];
    for(int r=0;r<4;r++){
      int mg = m0 + wm*32 + mf*16 + qd*4 + r;
      if(mg<1232){
        float v=acc[mf][nf][r]+bias;
        int bb=mg/77, l=mg-bb*77;
        if(ng<256) kb[((size_t)(bb*77+l))*256+ng]=f2bf(v);
        else vT[((size_t)(bb*256+(ng-256)))*96 + l]=f2bf(v);
      }
    }
  }
}

// ---------------- K7: attention FUSED with o-projection + residual ----------------
__global__ __launch_bounds__(256, 2) void k_attn(const u16* __restrict__ qg, const u16* __restrict__ kb,
    const u16* __restrict__ vT, const u16* __restrict__ woB, const float* __restrict__ bo,
    const float* __restrict__ x, float* __restrict__ outp){
  __shared__ u16 SM[37888];
  __shared__ float invr[128];
  u16* KVf = SM;
  u16* Pb  = SM + 24576;
  u16* Ol  = SM;
  int bid=blockIdx.x; int b=bid>>5, qt=bid&31; int p0=qt*128;
  int tid=threadIdx.x, w=tid>>6, lane=tid&63, ln=lane&15, qd=lane>>4;

  #pragma unroll
  for(int j=0;j<10;j++){
    int c = tid + j*256;
    int kt = c/320, rem = c - kt*320;
    int q2 = rem/80, l = rem - q2*80;
    int ls = l<77 ? l : 76;
    g2l16(kb + ((size_t)(b*77+ls)*256 + kt*32 + q2*8), &KVf[(size_t)c*8]);
  }
  bf16x8 qf[2][8];
  #pragma unroll
  for(int mf=0;mf<2;mf++){
    const u16* qsrc = qg + ((size_t)(b*HW_ + p0 + w*32 + mf*16 + ln))*256 + qd*8;
    #pragma unroll
    for(int kt=0;kt<8;kt++) qf[mf][kt] = ldfrag(qsrc + kt*32);
  }
  __syncthreads();

  f32x4 Sa[2][5]={};
  #pragma unroll
  for(int kt=0;kt<8;kt++){
    bf16x8 kf[5];
    #pragma unroll
    for(int nf=0;nf<5;nf++) kf[nf]=ldfrag(&KVf[((size_t)kt*320 + qd*80 + nf*16+ln)*8]);
    #pragma unroll
    for(int mf=0;mf<2;mf++)
      #pragma unroll
      for(int nf=0;nf<5;nf++)
        Sa[mf][nf]=__builtin_amdgcn_mfma_f32_16x16x32_bf16(qf[mf][kt],kf[nf],Sa[mf][nf],0,0,0);
  }
  if(ln>=13){
    #pragma unroll
    for(int mf=0;mf<2;mf++)
      #pragma unroll
      for(int r=0;r<4;r++) Sa[mf][4][r] = -1e30f;
  }
  float mrow[2][4];
  #pragma unroll
  for(int mf=0;mf<2;mf++)
    #pragma unroll
    for(int r=0;r<4;r++){
      float m = Sa[mf][0][r];
      #pragma unroll
      for(int nf=1;nf<5;nf++) m = fmaxf(m, Sa[mf][nf][r]);
      mrow[mf][r]=m;
    }
  #pragma unroll
  for(int off=1;off<16;off<<=1)
    #pragma unroll
    for(int mf=0;mf<2;mf++)
      #pragma unroll
      for(int r=0;r<4;r++) mrow[mf][r] = fmaxf(mrow[mf][r], __shfl_xor(mrow[mf][r], off, 64));
  float rs[2][4]={};
  u16 pe[2][5][4];
  #pragma unroll
  for(int mf=0;mf<2;mf++)
    #pragma unroll
    for(int nf=0;nf<5;nf++)
      #pragma unroll
      for(int r=0;r<4;r++){
        float e = __expf((Sa[mf][nf][r]-mrow[mf][r])*0.0625f);
        rs[mf][r]+=e; pe[mf][nf][r]=f2bf(e);
      }
  #pragma unroll
  for(int off=1;off<16;off<<=1)
    #pragma unroll
    for(int mf=0;mf<2;mf++)
      #pragma unroll
      for(int r=0;r<4;r++) rs[mf][r] += __shfl_xor(rs[mf][r], off, 64);
  #pragma unroll
  for(int mf=0;mf<2;mf++)
    #pragma unroll
    for(int nf=0;nf<5;nf++)
      #pragma unroll
      for(int r=0;r<4;r++) Pb[(w*32+mf*16+qd*4+r)*104 + nf*16+ln] = pe[mf][nf][r];
  {
    int row = tid>>1, j0 = (tid&1)*8;
    u16x8 z = {0,0,0,0,0,0,0,0};
    *(u16x8*)&Pb[row*104 + 80 + j0] = z;
  }
  if(ln==0){
    #pragma unroll
    for(int mf=0;mf<2;mf++)
      #pragma unroll
      for(int r=0;r<4;r++) invr[w*32+mf*16+qd*4+r] = 1.f/rs[mf][r];
  }
  __syncthreads();

  #pragma unroll
  for(int j=0;j<12;j++){
    int c = tid + j*256;
    int g = c>>7, co = c&127;
    int q2 = g&3, s5 = g>>2;
    int nh2 = s5>2 ? 1 : 0, kt2 = s5 - 3*nh2;
    g2l16(vT + ((size_t)(b*256 + nh2*128 + co)*96 + kt2*32 + q2*8), &KVf[(size_t)c*8]);
  }
  __syncthreads();

  f32x4 Oa[2][2][8]={};
  #pragma unroll
  for(int nh=0;nh<2;nh++){
    #pragma unroll
    for(int kt2=0;kt2<3;kt2++){
      bf16x8 pa[2], vf[8];
      #pragma unroll
      for(int mf=0;mf<2;mf++) pa[mf]=ldfrag(&Pb[(w*32+mf*16+ln)*104 + kt2*32+qd*8]);
      #pragma unroll
      for(int nf=0;nf<8;nf++) vf[nf]=ldfrag(&KVf[(((size_t)(nh*3+kt2)*4+qd)*128 + nf*16+ln)*8]);
      #pragma unroll
      for(int mf=0;mf<2;mf++)
        #pragma unroll
        for(int nf=0;nf<8;nf++)
          Oa[nh][mf][nf]=__builtin_amdgcn_mfma_f32_16x16x32_bf16(pa[mf],vf[nf],Oa[nh][mf][nf],0,0,0);
    }
  }
  __syncthreads();

  #pragma unroll
  for(int nh=0;nh<2;nh++)
    #pragma unroll
    for(int mf=0;mf<2;mf++)
      #pragma unroll
      for(int r=0;r<4;r++){
        int ml = w*32+mf*16+qd*4+r;
        float inv = invr[ml];
        #pragma unroll
        for(int nf=0;nf<8;nf++)
          Ol[ml*264 + nh*128 + nf*16 + ln] = f2bf(Oa[nh][mf][nf][r]*inv);
      }
  __syncthreads();

  f32x4 a2[4][8] = {};
  #pragma unroll 2
  for(int kt=0;kt<8;kt++){
    bf16x8 af2[4], bf2v[8];
    #pragma unroll
    for(int mf2=0;mf2<4;mf2++)
      af2[mf2] = ldfrag(woB + (size_t)(w*64+mf2*16+ln)*256 + kt*32 + qd*8);
    #pragma unroll
    for(int nf2=0;nf2<8;nf2++)
      bf2v[nf2] = ldfrag(&Ol[(nf2*16+ln)*264 + kt*32 + qd*8]);
    #pragma unroll
    for(int mf2=0;mf2<4;mf2++)
      #pragma unroll
      for(int nf2=0;nf2<8;nf2++)
        a2[mf2][nf2] = __builtin_amdgcn_mfma_f32_16x16x32_bf16(af2[mf2], bf2v[nf2], a2[mf2][nf2],0,0,0);
  }
  #pragma unroll
  for(int mf2=0;mf2<4;mf2++)
    #pragma unroll
    for(int r=0;r<4;r++){
      int cl = w*64 + mf2*16 + qd*4 + r;
      float bias = bo[cl];
      #pragma unroll
      for(int nf2=0;nf2<8;nf2++){
        int px = p0 + nf2*16 + ln;
        size_t idx = ((size_t)(b*C_+cl))*HW_ + px;
        outp[idx] = x[idx] + a2[mf2][nf2][r] + bias;
      }
    }
}

extern "C" void kernel_launch(void* const* d_in, const int* in_sizes, int n_in,
                              void* d_out, int out_size, void* d_ws, size_t ws_size,
                              hipStream_t stream){
  const float* x      = (const float*)d_in[0];
  const float* ctx    = (const float*)d_in[1];
  const float* conv_w = (const float*)d_in[2];
  const float* conv_b = (const float*)d_in[3];
  const float* gnw    = (const float*)d_in[4];
  const float* gnb    = (const float*)d_in[5];
  const float* wq     = (const float*)d_in[6];
  const float* bq     = (const float*)d_in[7];
  const float* wk     = (const float*)d_in[8];
  const float* bk     = (const float*)d_in[9];
  const float* wv     = (const float*)d_in[10];
  const float* bv     = (const float*)d_in[11];
  const float* wo     = (const float*)d_in[12];
  const float* bo     = (const float*)d_in[13];
  char* ws = (char*)d_ws;
  u16* xpT  = (u16*)(ws + 0);            // 35,684,352 ; reused as q after conv
  u16* wBt  = (u16*)(ws + 35684352);     //  1,179,648
  u16* wqB  = (u16*)(ws + 36864000);     //    131,072
  u16* wkvB = (u16*)(ws + 36995072);     //    786,432
  u16* woB  = (u16*)(ws + 37781504);     //    131,072
  u16* ctxB = (u16*)(ws + 37912576);     //  1,892,352
  u16* hbuf = (u16*)(ws + 39804928);     // 33,554,432 (fallback path only)
  u16* kbv  = (u16*)(ws + 73359360);     //    630,784
  u16* vT   = (u16*)(ws + 73990144);     //    786,432
  float* stats = (float*)(ws + 108331008); // 2048
  u16* qb = xpT;
  float* outp = (float*)d_out;

  k_prep  <<<9106, 256, 0, stream>>>(x, xpT, conv_w, wq, wo, wk, wv, ctx, wBt, wqB, woB, wkvB, ctxB, stats);
  {
    void* args[] = {(void*)&xpT, (void*)&wBt, (void*)&conv_b, (void*)&stats,
                    (void*)&wqB, (void*)&gnw, (void*)&gnb, (void*)&bq, (void*)&qb};
    hipError_t cerr = hipLaunchCooperativeKernel((const void*)k_cgq, dim3(512), dim3(256), args, 0, stream);
    if(cerr != hipSuccess){
      k_conv_fb<<<1024, 256, 0, stream>>>(xpT, wBt, conv_b, hbuf, stats);
      k_qgn_fb <<<512,  256, 0, stream>>>(hbuf, wqB, stats, gnw, gnb, bq, qb);
    }
  }
  k_kvproj<<<160,  256, 0, stream>>>(ctxB, wkvB, bk, bv, kbv, vT);
  k_attn  <<<512,  256, 0, stream>>>(qb, kbv, vT, woB, bo, x, outp);
}

// Round 9
// 340.374 us; speedup vs baseline: 1.4498x; 1.4498x over previous
//
#include <hip/hip_runtime.h>
#include <stdint.h>

#define B_  16
#define C_  256
#define HW_ 4096
#define Hp  66
#define PP  4356   // 66*66
#define EPS_ 1e-5f

typedef unsigned short u16;
typedef unsigned int   u32;
typedef __attribute__((ext_vector_type(4))) float  f32x4;
typedef __attribute__((ext_vector_type(8))) __bf16 bf16x8;
typedef __attribute__((ext_vector_type(8))) u16    u16x8;

__device__ __forceinline__ float bf2f(u16 u){ u32 x = ((u32)u)<<16; float f; __builtin_memcpy(&f,&x,4); return f; }
__device__ __forceinline__ u16 f2bf(float f){ u32 x; __builtin_memcpy(&x,&f,4); u32 r = x + 0x7fffu + ((x>>16)&1u); return (u16)(r>>16); }

__device__ __forceinline__ void g2l16(const void* g, void* l){
  __builtin_amdgcn_global_load_lds((__attribute__((address_space(1))) void*)(void*)g,
                                   (__attribute__((address_space(3))) void*)l, 16, 0, 0);
}
__device__ __forceinline__ bf16x8 ldfrag(const u16* p){
  u16x8 r = *(const u16x8*)p;
  return __builtin_bit_cast(bf16x8, r);
}

// ---------------- K0: pad+transpose x AND repack weights (merged, block-range split) -----
// Layouts (conflict-free atom-major LDS staging for k_conv):
//   xpT: [b][ci(8)][atom(4)][PP pixels][8ch]
//   wBt: [ci(8)][tap(9)][atom(4)][co(256)][8ch]
__global__ __launch_bounds__(256) void k_prep(const float* __restrict__ x, u16* __restrict__ xpT,
    const float* __restrict__ conv_w, const float* __restrict__ wq, const float* __restrict__ wo,
    const float* __restrict__ wk, const float* __restrict__ wv, const float* __restrict__ ctx,
    u16* __restrict__ wBt, u16* __restrict__ wqB, u16* __restrict__ woB,
    u16* __restrict__ wkvB, u16* __restrict__ ctxB, float* __restrict__ stats){
  __shared__ float Lt[64*65];
  int bid = blockIdx.x; int tid = threadIdx.x;
  if(bid >= 1056){
    int i = (bid-1056)*256 + tid;
    if(i < 589824){
      int j = i&7, co = (i>>3)&255, atom = (i>>11)&3, g = i>>13;   // g in [0,72)
      int t = g%9, cic = g/9;
      int ciF = cic*32 + atom*8 + j;
      wBt[i] = f2bf(conv_w[(co*256+ciF)*9 + t]); return;
    }
    i -= 589824;
    if(i < 65536){ wqB[i] = f2bf(wq[i]); return; } i -= 65536;
    if(i < 65536){ woB[i] = f2bf(wo[i]); return; } i -= 65536;
    if(i < 196608){ wkvB[i] = f2bf(wk[i]); return; } i -= 196608;
    if(i < 196608){ wkvB[196608+i] = f2bf(wv[i]); return; } i -= 196608;
    if(i < 946176){ ctxB[i] = f2bf(ctx[i]); return; } i -= 946176;
    if(i < 512){ stats[i] = 0.f; }
    return;
  }
  int b = bid/66, hh = bid - b*66;
  if(hh==0 || hh==65){
    for(int i=tid;i<32*264;i+=256){
      int pl = i/264, off = i - pl*264;
      u32* p = (u32*)(xpT + ((size_t)(b*32+pl)*PP + (size_t)hh*Hp)*8);
      p[off] = 0u;
    }
    return;
  }
  {
    int pl = tid>>3, q = tid&7;
    size_t base = ((size_t)(b*32+pl)*PP + (size_t)hh*Hp + (q>=4?65:0))*8;
    ((u32*)(xpT + base))[q&3] = 0u;
  }
  int h = hh-1;
  for(int cc=0; cc<4; cc++){
    int c0=cc*64;
    int ci = tid>>2, w0 = (tid&3)*16;
    const float* xs = x + ((size_t)(b*C_ + c0+ci)*HW_) + h*64 + w0;
    for(int j=0;j<4;j++){
      float4 v = *(const float4*)(xs + j*4);
      Lt[ci*65 + w0 + j*4 + 0] = v.x;
      Lt[ci*65 + w0 + j*4 + 1] = v.y;
      Lt[ci*65 + w0 + j*4 + 2] = v.z;
      Lt[ci*65 + w0 + j*4 + 3] = v.w;
    }
    __syncthreads();
    int w = tid>>2, cj = (tid&3)*16;
    union { u16 u[16]; uint4 v[2]; } outu;
    for(int j=0;j<16;j++) outu.u[j] = f2bf(Lt[(cj+j)*65 + w]);
    int chan = c0 + cj;
    int cic = chan>>5, at0 = (chan>>3)&3;
    u16* dst = xpT + (((size_t)(b*8+cic)*4 + at0)*PP + (size_t)hh*Hp + w + 1)*8;
    *(uint4*)dst = outu.v[0];
    *(uint4*)(dst + (size_t)PP*8) = outu.v[1];
    __syncthreads();
  }
}

// ---------------- K2: conv implicit GEMM (proven basin-best variant) ----------------
__global__ __launch_bounds__(256, 3) void k_conv(const u16* __restrict__ xpT, const u16* __restrict__ wBt,
    const float* __restrict__ conv_b, u16* __restrict__ h, float* __restrict__ stats){
  __shared__ u16 As[2][264*32];   // 33,792 B
  __shared__ u16 Bs[2][128*32];   // 16,384 B
  int bid0 = blockIdx.x;
  int l = (bid0 & 7)*128 + (bid0 >> 3);    // chunked XCD swizzle, 1024 % 8 == 0 (bijective)
  int b = l >> 6, hp = (l >> 1) & 31, nh = l & 1;
  int tid = threadIdx.x;
  int w = tid>>6, lane = tid&63, ln = lane&15, qd = lane>>4;
  int wm = w&1, wn = w>>1;
  f32x4 acc[4][4] = {};
  int hr_[4], wp_[4];
  #pragma unroll
  for(int mf=0;mf<4;mf++){ int p = wm*64 + mf*16 + ln; hr_[mf] = p>>6; wp_[mf] = p&63; }

  #pragma unroll
  for(int r=0;r<5;r++){
    int c = r*256 + tid;
    if(c < 1056){
      int atom = c/264, ipix = c - atom*264;
      g2l16(xpT + (((size_t)(b*8+0)*4 + atom)*PP + hp*132 + ipix)*8, &As[0][c*8]);
    }
  }
  #pragma unroll
  for(int r=0;r<2;r++){
    int c = r*256 + tid;
    int atom = c>>7, col = c&127;
    g2l16(wBt + ((size_t)atom*2048 + (nh*128+col)*8), &Bs[0][c*8]);
  }
  __syncthreads();

  int cb = 0;
  for(int ci=0; ci<8; ci++){
    int ca = ci&1;
    for(int t=0;t<9;t++){
      int tn = t+1, cin = ci;
      if(tn==9){ tn=0; cin=ci+1; }
      if(cin < 8){
        #pragma unroll
        for(int r=0;r<2;r++){
          int c = r*256 + tid;
          int atom = c>>7, col = c&127;
          g2l16(wBt + (((size_t)(cin*9+tn)*4 + atom)*2048 + (nh*128+col)*8), &Bs[cb^1][c*8]);
        }
      }
      if(t<5 && ci<7){
        int c = t*256 + tid;
        if(c < 1056){
          int atom = c/264, ipix = c - atom*264;
          g2l16(xpT + (((size_t)(b*8+ci+1)*4 + atom)*PP + hp*132 + ipix)*8, &As[ca^1][c*8]);
        }
      }
      int dy = (t*11)>>5, dx = t - dy*3;
      bf16x8 af[4], bfv[4];
      #pragma unroll
      for(int mf=0;mf<4;mf++){
        int ipix = (hr_[mf]+dy)*66 + wp_[mf] + dx;
        af[mf] = ldfrag(&As[ca][(qd*264 + ipix)*8]);
      }
      #pragma unroll
      for(int nf=0;nf<4;nf++) bfv[nf] = ldfrag(&Bs[cb][(qd*128 + wn*64+nf*16+ln)*8]);
      #pragma unroll
      for(int mf=0;mf<4;mf++)
        #pragma unroll
        for(int nf=0;nf<4;nf++)
          acc[mf][nf] = __builtin_amdgcn_mfma_f32_16x16x32_bf16(af[mf], bfv[nf], acc[mf][nf], 0,0,0);
      __syncthreads();
      cb ^= 1;
    }
  }
  float s[2]={0,0}, q[2]={0,0};
  int p0 = hp*128;
  for(int nf=0;nf<4;nf++){
    int n = nh*128 + wn*64 + nf*16 + ln;
    float bias = conv_b[n];
    for(int mf=0;mf<4;mf++){
      for(int r=0;r<4;r++){
        int p = wm*64 + mf*16 + qd*4 + r;
        float v = acc[mf][nf][r] + bias;
        h[((size_t)(b*HW_ + p0 + p))*C_ + n] = f2bf(v);
        s[nf>>1]+=v; q[nf>>1]+=v*v;
      }
    }
  }
  for(int off=32;off>=1;off>>=1){
    #pragma unroll
    for(int g=0;g<2;g++){ s[g]+=__shfl_down(s[g],off,64); q[g]+=__shfl_down(q[g],off,64); }
  }
  if(lane==0){
    #pragma unroll
    for(int g=0;g<2;g++){
      int gg = nh*4 + wn*2 + g;
      atomicAdd(&stats[(b*8 + gg)*2+0], s[g]);
      atomicAdd(&stats[(b*8 + gg)*2+1], q[g]);
    }
  }
}

// ---------------- K5: fused GN+SiLU+qproj: q = silu(gn(h)) @ wq^T + bq ----------------
__global__ __launch_bounds__(256, 2) void k_qgn(const u16* __restrict__ hbuf, const u16* __restrict__ wqB,
    const float* __restrict__ stats, const float* __restrict__ gnw, const float* __restrict__ gnb,
    const float* __restrict__ bq, u16* __restrict__ qb){
  __shared__ u16 As[128*32];
  __shared__ u16 Bs[256*32];
  int mt = blockIdx.x;
  int b = mt >> 5;
  int tid = threadIdx.x;
  int w = tid>>6, lane = tid&63, ln = lane&15, qd = lane>>4;
  int wm = w&1, wn = w>>1;
  int pr = tid>>1, half = tid&1;
  const u16* hsrc = hbuf + ((size_t)(mt*128+pr))*256 + half*16;
  f32x4 acc[4][8] = {};
  uint4 ra0, ra1, rb0, rb1;
  ra0 = *(const uint4*)(hsrc);
  ra1 = *(const uint4*)(hsrc + 8);
  for(int kt=0; kt<8; kt++){
    float sm = stats[(b*8+kt)*2], qm = stats[(b*8+kt)*2+1];
    float mean = sm*(1.f/131072.f);
    float rstd = rsqrtf(qm*(1.f/131072.f) - mean*mean + EPS_);
    int c0 = kt*32 + half*16;
    float4 gw0 = *(const float4*)(gnw+c0), gw1 = *(const float4*)(gnw+c0+4);
    float4 gw2 = *(const float4*)(gnw+c0+8), gw3 = *(const float4*)(gnw+c0+12);
    float4 gb0 = *(const float4*)(gnb+c0), gb1 = *(const float4*)(gnb+c0+4);
    float4 gb2 = *(const float4*)(gnb+c0+8), gb3 = *(const float4*)(gnb+c0+12);
    float gwv[16] = {gw0.x,gw0.y,gw0.z,gw0.w, gw1.x,gw1.y,gw1.z,gw1.w,
                     gw2.x,gw2.y,gw2.z,gw2.w, gw3.x,gw3.y,gw3.z,gw3.w};
    float gbv[16] = {gb0.x,gb0.y,gb0.z,gb0.w, gb1.x,gb1.y,gb1.z,gb1.w,
                     gb2.x,gb2.y,gb2.z,gb2.w, gb3.x,gb3.y,gb3.z,gb3.w};
    u16 inu[16];
    ((uint4*)inu)[0] = ra0; ((uint4*)inu)[1] = ra1;
    u16 outu[16];
    #pragma unroll
    for(int j=0;j<16;j++){
      float v = bf2f(inu[j]);
      v = (v-mean)*rstd*gwv[j] + gbv[j];
      float s = v/(1.f+__expf(-v));
      outu[j] = f2bf(s);
    }
    u16* adst = &As[pr*32 + half*16];
    ((uint4*)adst)[0] = ((uint4*)outu)[0];
    ((uint4*)adst)[1] = ((uint4*)outu)[1];
    #pragma unroll
    for(int r=0;r<4;r++){
      int c = r*256 + tid;
      int co = c>>2, atom = c&3;
      g2l16(wqB + (size_t)co*256 + kt*32 + atom*8, &Bs[c*8]);
    }
    if(kt<7){
      rb0 = *(const uint4*)(hsrc + (kt+1)*32);
      rb1 = *(const uint4*)(hsrc + (kt+1)*32 + 8);
    }
    __syncthreads();
    bf16x8 af[4], bfv[8];
    #pragma unroll
    for(int mf=0;mf<4;mf++) af[mf] = ldfrag(&As[(wm*64+mf*16+ln)*32 + qd*8]);
    #pragma unroll
    for(int nf=0;nf<8;nf++) bfv[nf] = ldfrag(&Bs[(wn*128+nf*16+ln)*32 + qd*8]);
    #pragma unroll
    for(int mf=0;mf<4;mf++)
      #pragma unroll
      for(int nf=0;nf<8;nf++)
        acc[mf][nf] = __builtin_amdgcn_mfma_f32_16x16x32_bf16(af[mf], bfv[nf], acc[mf][nf], 0,0,0);
    __syncthreads();
    ra0 = rb0; ra1 = rb1;
  }
  for(int nf=0;nf<8;nf++){
    int n = wn*128 + nf*16 + ln;
    float bias = bq[n];
    for(int mf=0;mf<4;mf++){
      for(int r=0;r<4;r++){
        int ml = wm*64 + mf*16 + qd*4 + r;
        qb[((size_t)(mt*128+ml))*256 + n] = f2bf(acc[mf][nf][r]+bias);
      }
    }
  }
}

// ---------------- K6: k,v = ctx @ {wk,wv}^T + b, 64x64 tiles, 160 blocks ----------------
__global__ __launch_bounds__(256) void k_kvproj(const u16* __restrict__ ctxB, const u16* __restrict__ wkvB,
    const float* __restrict__ bk, const float* __restrict__ bv,
    u16* __restrict__ kb, u16* __restrict__ vT){
  __shared__ u16 As[64*128];
  __shared__ u16 Bs[64*128];
  int bid = blockIdx.x;
  int nt = bid & 7, mt = bid >> 3;
  int n0 = nt*64, m0 = mt*64;
  int tid=threadIdx.x, w=tid>>6, lane=tid&63, ln=lane&15, qd=lane>>4;
  int wm = w&1, wn = w>>1;
  f32x4 acc[2][2]={};
  for(int kt=0;kt<6;kt++){
    #pragma unroll
    for(int r=0;r<4;r++){
      int c = r*256 + tid;
      int row = c>>4, atom = c&15;
      g2l16(ctxB + ((size_t)(m0+row)*768 + kt*128 + atom*8), &As[c*8]);
      g2l16(wkvB + ((size_t)(n0+row)*768 + kt*128 + atom*8), &Bs[c*8]);
    }
    __syncthreads();
    #pragma unroll
    for(int kk=0;kk<4;kk++){
      bf16x8 af[2], bfv[2];
      #pragma unroll
      for(int mf=0;mf<2;mf++) af[mf]=ldfrag(&As[(wm*32+mf*16+ln)*128 + kk*32 + qd*8]);
      #pragma unroll
      for(int nf=0;nf<2;nf++) bfv[nf]=ldfrag(&Bs[(wn*32+nf*16+ln)*128 + kk*32 + qd*8]);
      #pragma unroll
      for(int mf=0;mf<2;mf++)
        #pragma unroll
        for(int nf=0;nf<2;nf++)
          acc[mf][nf]=__builtin_amdgcn_mfma_f32_16x16x32_bf16(af[mf],bfv[nf],acc[mf][nf],0,0,0);
    }
    __syncthreads();
  }
  for(int mf=0;mf<2;mf++) for(int nf=0;nf<2;nf++){
    int ng = n0 + wn*32 + nf*16 + ln;
    float bias = ng<256 ? bk[ng] : bv[ng-256];
    for(int r=0;r<4;r++){
      int mg = m0 + wm*32 + mf*16 + qd*4 + r;
      if(mg<1232){
        float v=acc[mf][nf][r]+bias;
        int bb=mg/77, l=mg-bb*77;
        if(ng<256) kb[((size_t)(bb*77+l))*256+ng]=f2bf(v);
        else vT[((size_t)(bb*256+(ng-256)))*96 + l]=f2bf(v);
      }
    }
  }
}

// ---------------- K7: attention FUSED with o-projection + residual (+ setprio T5) -------
__global__ __launch_bounds__(256, 2) void k_attn(const u16* __restrict__ qg, const u16* __restrict__ kb,
    const u16* __restrict__ vT, const u16* __restrict__ woB, const float* __restrict__ bo,
    const float* __restrict__ x, float* __restrict__ outp){
  __shared__ u16 SM[37888];       // 75,776 B shared pool
  __shared__ float invr[128];
  u16* KVf = SM;                  // K-phase: [kt8][qd4][80][8]; V-phase: [s6][qd4][128][8]
  u16* Pb  = SM + 24576;          // [128][104]
  u16* Ol  = SM;                  // O bf16 [128 px][264 pad] (overlays after PV)
  int bid=blockIdx.x; int b=bid>>5, qt=bid&31; int p0=qt*128;
  int tid=threadIdx.x, w=tid>>6, lane=tid&63, ln=lane&15, qd=lane>>4;

  #pragma unroll
  for(int j=0;j<10;j++){
    int c = tid + j*256;
    int kt = c/320, rem = c - kt*320;
    int q2 = rem/80, l = rem - q2*80;
    int ls = l<77 ? l : 76;
    g2l16(kb + ((size_t)(b*77+ls)*256 + kt*32 + q2*8), &KVf[(size_t)c*8]);
  }
  bf16x8 qf[2][8];
  #pragma unroll
  for(int mf=0;mf<2;mf++){
    const u16* qsrc = qg + ((size_t)(b*HW_ + p0 + w*32 + mf*16 + ln))*256 + qd*8;
    #pragma unroll
    for(int kt=0;kt<8;kt++) qf[mf][kt] = ldfrag(qsrc + kt*32);
  }
  __syncthreads();                        // barrier 1: K staged

  f32x4 Sa[2][5]={};
  __builtin_amdgcn_s_setprio(1);
  #pragma unroll
  for(int kt=0;kt<8;kt++){
    bf16x8 kf[5];
    #pragma unroll
    for(int nf=0;nf<5;nf++) kf[nf]=ldfrag(&KVf[((size_t)kt*320 + qd*80 + nf*16+ln)*8]);
    #pragma unroll
    for(int mf=0;mf<2;mf++)
      #pragma unroll
      for(int nf=0;nf<5;nf++)
        Sa[mf][nf]=__builtin_amdgcn_mfma_f32_16x16x32_bf16(qf[mf][kt],kf[nf],Sa[mf][nf],0,0,0);
  }
  __builtin_amdgcn_s_setprio(0);
  if(ln>=13){
    #pragma unroll
    for(int mf=0;mf<2;mf++)
      #pragma unroll
      for(int r=0;r<4;r++) Sa[mf][4][r] = -1e30f;
  }
  float mrow[2][4];
  #pragma unroll
  for(int mf=0;mf<2;mf++)
    #pragma unroll
    for(int r=0;r<4;r++){
      float m = Sa[mf][0][r];
      #pragma unroll
      for(int nf=1;nf<5;nf++) m = fmaxf(m, Sa[mf][nf][r]);
      mrow[mf][r]=m;
    }
  #pragma unroll
  for(int off=1;off<16;off<<=1)
    #pragma unroll
    for(int mf=0;mf<2;mf++)
      #pragma unroll
      for(int r=0;r<4;r++) mrow[mf][r] = fmaxf(mrow[mf][r], __shfl_xor(mrow[mf][r], off, 64));
  float rs[2][4]={};
  u16 pe[2][5][4];
  #pragma unroll
  for(int mf=0;mf<2;mf++)
    #pragma unroll
    for(int nf=0;nf<5;nf++)
      #pragma unroll
      for(int r=0;r<4;r++){
        float e = __expf((Sa[mf][nf][r]-mrow[mf][r])*0.0625f);
        rs[mf][r]+=e; pe[mf][nf][r]=f2bf(e);
      }
  #pragma unroll
  for(int off=1;off<16;off<<=1)
    #pragma unroll
    for(int mf=0;mf<2;mf++)
      #pragma unroll
      for(int r=0;r<4;r++) rs[mf][r] += __shfl_xor(rs[mf][r], off, 64);
  #pragma unroll
  for(int mf=0;mf<2;mf++)
    #pragma unroll
    for(int nf=0;nf<5;nf++)
      #pragma unroll
      for(int r=0;r<4;r++) Pb[(w*32+mf*16+qd*4+r)*104 + nf*16+ln] = pe[mf][nf][r];
  {
    int row = tid>>1, j0 = (tid&1)*8;
    u16x8 z = {0,0,0,0,0,0,0,0};
    *(u16x8*)&Pb[row*104 + 80 + j0] = z;
  }
  if(ln==0){
    #pragma unroll
    for(int mf=0;mf<2;mf++)
      #pragma unroll
      for(int r=0;r<4;r++) invr[w*32+mf*16+qd*4+r] = 1.f/rs[mf][r];
  }
  __syncthreads();                        // barrier 2

  #pragma unroll
  for(int j=0;j<12;j++){
    int c = tid + j*256;
    int g = c>>7, co = c&127;
    int q2 = g&3, s5 = g>>2;
    int nh2 = s5>2 ? 1 : 0, kt2 = s5 - 3*nh2;
    g2l16(vT + ((size_t)(b*256 + nh2*128 + co)*96 + kt2*32 + q2*8), &KVf[(size_t)c*8]);
  }
  __syncthreads();                        // barrier 3: V staged

  f32x4 Oa[2][2][8]={};
  __builtin_amdgcn_s_setprio(1);
  #pragma unroll
  for(int nh=0;nh<2;nh++){
    #pragma unroll
    for(int kt2=0;kt2<3;kt2++){
      bf16x8 pa[2], vf[8];
      #pragma unroll
      for(int mf=0;mf<2;mf++) pa[mf]=ldfrag(&Pb[(w*32+mf*16+ln)*104 + kt2*32+qd*8]);
      #pragma unroll
      for(int nf=0;nf<8;nf++) vf[nf]=ldfrag(&KVf[(((size_t)(nh*3+kt2)*4+qd)*128 + nf*16+ln)*8]);
      #pragma unroll
      for(int mf=0;mf<2;mf++)
        #pragma unroll
        for(int nf=0;nf<8;nf++)
          Oa[nh][mf][nf]=__builtin_amdgcn_mfma_f32_16x16x32_bf16(pa[mf],vf[nf],Oa[nh][mf][nf],0,0,0);
    }
  }
  __builtin_amdgcn_s_setprio(0);
  __syncthreads();                        // barrier 4: Pb/KVf dead

  #pragma unroll
  for(int nh=0;nh<2;nh++)
    #pragma unroll
    for(int mf=0;mf<2;mf++)
      #pragma unroll
      for(int r=0;r<4;r++){
        int ml = w*32+mf*16+qd*4+r;
        float inv = invr[ml];
        #pragma unroll
        for(int nf=0;nf<8;nf++)
          Ol[ml*264 + nh*128 + nf*16 + ln] = f2bf(Oa[nh][mf][nf][r]*inv);
      }
  __syncthreads();                        // barrier 5: O visible

  f32x4 a2[4][8] = {};
  __builtin_amdgcn_s_setprio(1);
  #pragma unroll 2
  for(int kt=0;kt<8;kt++){
    bf16x8 af2[4], bf2v[8];
    #pragma unroll
    for(int mf2=0;mf2<4;mf2++)
      af2[mf2] = ldfrag(woB + (size_t)(w*64+mf2*16+ln)*256 + kt*32 + qd*8);
    #pragma unroll
    for(int nf2=0;nf2<8;nf2++)
      bf2v[nf2] = ldfrag(&Ol[(nf2*16+ln)*264 + kt*32 + qd*8]);
    #pragma unroll
    for(int mf2=0;mf2<4;mf2++)
      #pragma unroll
      for(int nf2=0;nf2<8;nf2++)
        a2[mf2][nf2] = __builtin_amdgcn_mfma_f32_16x16x32_bf16(af2[mf2], bf2v[nf2], a2[mf2][nf2],0,0,0);
  }
  __builtin_amdgcn_s_setprio(0);
  #pragma unroll
  for(int mf2=0;mf2<4;mf2++)
    #pragma unroll
    for(int r=0;r<4;r++){
      int cl = w*64 + mf2*16 + qd*4 + r;
      float bias = bo[cl];
      #pragma unroll
      for(int nf2=0;nf2<8;nf2++){
        int px = p0 + nf2*16 + ln;
        size_t idx = ((size_t)(b*C_+cl))*HW_ + px;
        outp[idx] = x[idx] + a2[mf2][nf2][r] + bias;
      }
    }
}

extern "C" void kernel_launch(void* const* d_in, const int* in_sizes, int n_in,
                              void* d_out, int out_size, void* d_ws, size_t ws_size,
                              hipStream_t stream){
  const float* x      = (const float*)d_in[0];
  const float* ctx    = (const float*)d_in[1];
  const float* conv_w = (const float*)d_in[2];
  const float* conv_b = (const float*)d_in[3];
  const float* gnw    = (const float*)d_in[4];
  const float* gnb    = (const float*)d_in[5];
  const float* wq     = (const float*)d_in[6];
  const float* bq     = (const float*)d_in[7];
  const float* wk     = (const float*)d_in[8];
  const float* bk     = (const float*)d_in[9];
  const float* wv     = (const float*)d_in[10];
  const float* bv     = (const float*)d_in[11];
  const float* wo     = (const float*)d_in[12];
  const float* bo     = (const float*)d_in[13];
  char* ws = (char*)d_ws;
  u16* xpT  = (u16*)(ws + 0);            // 35,684,352 ; reused as q after conv
  u16* wBt  = (u16*)(ws + 35684352);     //  1,179,648
  u16* wqB  = (u16*)(ws + 36864000);     //    131,072
  u16* wkvB = (u16*)(ws + 36995072);     //    786,432
  u16* woB  = (u16*)(ws + 37781504);     //    131,072
  u16* ctxB = (u16*)(ws + 37912576);     //  1,892,352
  u16* hbuf = (u16*)(ws + 39804928);     // 33,554,432 (raw conv output)
  u16* kbv  = (u16*)(ws + 73359360);     //    630,784
  u16* vT   = (u16*)(ws + 73990144);     //    786,432
  float* stats = (float*)(ws + 108331008); // 2048
  u16* qb = xpT;
  float* outp = (float*)d_out;

  k_prep  <<<9106, 256, 0, stream>>>(x, xpT, conv_w, wq, wo, wk, wv, ctx, wBt, wqB, woB, wkvB, ctxB, stats);
  k_conv  <<<1024, 256, 0, stream>>>(xpT, wBt, conv_b, hbuf, stats);
  k_qgn   <<<512,  256, 0, stream>>>(hbuf, wqB, stats, gnw, gnb, bq, qb);
  k_kvproj<<<160,  256, 0, stream>>>(ctxB, wkvB, bk, bv, kbv, vT);
  k_attn  <<<512,  256, 0, stream>>>(qb, kbv, vT, woB, bo, x, outp);
}